// Round 6
// baseline (140.090 us; speedup 1.0000x reference)
//
#include <hip/hip_runtime.h>

// ---------------------------------------------------------------------------
// EnhancedBlockGabor on MI355X (gfx950)
//   prep     : x -> 2 column-phase-shifted padded bf16 replicas; filters ->
//              A bf16 [48][256]; w1 -> bf16 [32][32][32]; zero stats
//   conv_mix : per (b,h) block, 32 channels; per channel stage 16 rows x 2
//              phase replicas into LDS (coalesced, double-buffered), gather
//              B-fragments (batched ds_read2_b32), mfma conv + |.| +
//              mixing GEMM; epilogue: y store + fused instance-norm stats
//   inorm2   : normalize + H<->W transpose via 32x32 LDS tiles
// b1 ignored: per-channel constant cancels under instance norm.
// R6: all conv LDS accesses rewritten as 32-bit array indexing on a
// __shared__ dword array (R5 used char* arithmetic with runtime parity --
// suspected failed addrspace inference => flat ops + 64-bit address VALU,
// matching the unexplained ~700 VALU inst/wave-c-iter at VALUBusy 50%).
// B-fragments batched into 64 pinned VGPRs before the MFMA section.
// ---------------------------------------------------------------------------

typedef __attribute__((ext_vector_type(8))) short bfx8;
typedef __attribute__((ext_vector_type(4))) float fx4;
typedef __attribute__((ext_vector_type(4))) unsigned ux4;

#define NREP   2
#define RPITCH 144
#define RROWS  144
#define IMG_SH (RROWS * RPITCH)            // 20736 shorts per padded image
#define REP_SH (128 * IMG_SH)              // shorts per replica
#define XREP_SH (NREP * REP_SH)

#define A_OFF    ((size_t)XREP_SH * 2)
#define W1B_OFF  (A_OFF + (size_t)48 * 256 * 2)
#define YP_OFF   (W1B_OFF + (size_t)32 * 32 * 32 * 2)
#define ST_OFF   (YP_OFF + (size_t)128 * 16384 * 4)
// total ws: ~19.3 MiB

// LDS staging geometry (dwords): per buffer 2 replicas; replica stride 1296 dw
// (== 16 mod 32 banks -> phase-replica reads stay 2-way = free); 1152 dw used.
#define STG_REP_DW 1296
#define STG_BUF_DW (2 * STG_REP_DW)        // 2592 dw per buffer

__device__ __forceinline__ unsigned short f2bf(float f) {
    unsigned u = __float_as_uint(f);
    u = (u + 0x7FFFu + ((u >> 16) & 1u)) >> 16;   // RTNE
    return (unsigned short)u;
}

// ---- merged prep: 2 replicas + A + w1b + stats-zero ----------------------
__global__ void prep(const float* __restrict__ x, const float* __restrict__ filt,
                     const float* __restrict__ w1, unsigned* __restrict__ xrep,
                     unsigned short* __restrict__ A, unsigned short* __restrict__ w1b,
                     float* __restrict__ stats)
{
    const int bid = blockIdx.x;
    if (bid < 2048) {
        const int DW_PER_ROW = RPITCH / 2;             // 72
        const int DW_PER_IMG = IMG_SH / 2;             // 10368
        const int DW_PER_REP = REP_SH / 2;             // 1,327,104
        const int total = NREP * DW_PER_REP;
        for (int i = bid * 256 + threadIdx.x; i < total; i += 2048 * 256) {
            int phi  = i / DW_PER_REP;                 // 0 or 1
            int rem  = i - phi * DW_PER_REP;
            int img  = rem / DW_PER_IMG;
            int rem2 = rem - img * DW_PER_IMG;
            int r    = rem2 / DW_PER_ROW;
            int pd   = rem2 - r * DW_PER_ROW;
            int c0   = 2 * pd + phi;                   // padded col of lo short
            float v0 = 0.f, v1 = 0.f;
            int rr = r - 7;
            if (rr >= 0 && rr < 128) {
                const float* row = x + ((size_t)img * 128 + rr) * 128;
                int cc0 = c0 - 7;
                if (cc0 >= 0 && cc0 < 128) v0 = row[cc0];
                int cc1 = c0 - 6;
                if (cc1 >= 0 && cc1 < 128) v1 = row[cc1];
            }
            xrep[i] = (unsigned)f2bf(v0) | ((unsigned)f2bf(v1) << 16);
        }
    } else {
        int t = (bid - 2048) * 256 + threadIdx.x;
        if (t < 48 * 256) {
            int f = t >> 8, k = t & 255;
            int ky = k >> 4, kx = k & 15;
            float v = 0.f;
            if (ky < 15 && kx < 15) v = filt[(f * 15 + ky) * 15 + kx];
            A[t] = f2bf(v);
        } else if (t < 48 * 256 + 32 * 32 * 32) {
            int j = t - 48 * 256;
            int c = j >> 10, o = (j >> 5) & 31, so = j & 31;
            float v = (so < 24) ? w1[o * 768 + c * 24 + so] : 0.f;
            w1b[j] = f2bf(v);
        } else if (t < 48 * 256 + 32 * 32 * 32 + 256) {
            stats[t - (48 * 256 + 32 * 32 * 32)] = 0.f;
        }
    }
}

// ---- fused conv + magnitude + channel-mix + stats ------------------------
// grid 512 = 4 b x 128 h, XCD-swizzled. 2 blocks/CU, one pass.
__global__ void __attribute__((amdgpu_waves_per_eu(2, 2)))
__launch_bounds__(256)
conv_mix(const unsigned short* __restrict__ xrep,
         const unsigned short* __restrict__ Aw,
         const unsigned short* __restrict__ w1b,
         float* __restrict__ ypart, float* __restrict__ stats)
{
    __shared__ unsigned stagew[2 * STG_BUF_DW];    // 20736 B, dword-indexed
    __shared__ unsigned mag_lds[4][32][20];        // 10240 B [wave][px][pad20]
    __shared__ float stat_lds[4][4][16];           // 1 KB

    const int tid  = threadIdx.x;
    const int lane = tid & 63;
    const int wave = tid >> 6;
    const int n    = lane & 15;                    // MFMA row(A) / col(B,D)
    const int q    = lane >> 4;                    // MFMA k-octet / D row group

    const int bid = blockIdx.x;                    // xcd = bid & 7
    const int b   = (bid >> 1) & 3;
    const int h   = (bid & 1) * 64 + (bid >> 3);

    if (lane < 32) {                               // zero so=24..31 pads
        ux4 z4 = {0u, 0u, 0u, 0u};
        *(ux4*)&mag_lds[wave][lane][12] = z4;
    }

    // A fragments pinned (land in AGPRs; MFMA reads A from AGPR on gfx950)
    ux4 afr[3][8];
#pragma unroll
    for (int mt = 0; mt < 3; ++mt)
#pragma unroll
        for (int s = 0; s < 8; ++s)
            afr[mt][s] = *(const ux4*)(Aw + ((mt * 16 + n) * 256 + s * 32 + q * 8));
#pragma unroll
    for (int mt = 0; mt < 3; ++mt)
#pragma unroll
        for (int s = 0; s < 8; ++s)
            asm volatile("" : "+v"(afr[mt][s]));

    const int px0 = wave * 32;
    const int p   = n & 1;                         // LDS phase replica
    // fragment base, in dwords within one buffer (all offsets from here are
    // compile-time: + s*144 + t*8)
    const int fbase = p * STG_REP_DW + (q >> 1) * 72 +
                      ((px0 + (n - p) + 8 * (q & 1)) >> 1);

    // staging slot addressing: 16B slots; 288 slots per replica
    const int s1p  = (tid + 256) >= 288;           // slot1 replica
    const int off1 = tid + 256 - (s1p ? 288 : 0);
    const size_t ib0 = ((size_t)(b * 32) * RROWS + h) * RPITCH;   // shorts, ch0

    const fx4 zero4 = {0.f, 0.f, 0.f, 0.f};
    fx4 yacc[2][2];
#pragma unroll
    for (int mt = 0; mt < 2; ++mt)
#pragma unroll
        for (int t = 0; t < 2; ++t) yacc[mt][t] = zero4;

    // prologue: stage channel 0 into buf 0
    {
        const unsigned short* g = xrep + ib0;
        ux4 v0 = *(const ux4*)(g + tid * 8);
        ux4 v1 = *(const ux4*)(g + (size_t)s1p * REP_SH + off1 * 8);
        ux4 v2 = {0u, 0u, 0u, 0u};
        if (tid < 64) v2 = *(const ux4*)(g + REP_SH + (tid + 224) * 8);
        *(ux4*)&stagew[tid * 4] = v0;
        *(ux4*)&stagew[s1p * STG_REP_DW + off1 * 4] = v1;
        if (tid < 64) *(ux4*)&stagew[STG_REP_DW + (tid + 224) * 4] = v2;
    }
    __syncthreads();

    for (int c = 0; c < 32; ++c) {
        // issue staging loads for channel c+1 (land during compute)
        ux4 nv0, nv1, nv2;
        if (c < 31) {
            const unsigned short* g = xrep + ib0 + (size_t)(c + 1) * IMG_SH;
            nv0 = *(const ux4*)(g + tid * 8);
            nv1 = *(const ux4*)(g + (size_t)s1p * REP_SH + off1 * 8);
            if (tid < 64) nv2 = *(const ux4*)(g + REP_SH + (tid + 224) * 8);
        }

        bfx8 wf[2];
#pragma unroll
        for (int mt = 0; mt < 2; ++mt)
            wf[mt] = *(const bfx8*)(w1b + ((c * 32 + mt * 16 + n) * 32 + q * 8));

        // batch-load ALL 16 B-fragments from LDS (ds_read2_b32 pairs), pin
        const int fb = (c & 1) * STG_BUF_DW + fbase;
        ux4 braw[2][8];
#pragma unroll
        for (int s = 0; s < 8; ++s)
#pragma unroll
            for (int t = 0; t < 2; ++t) {
                const int ix = fb + s * 144 + t * 8;
                ux4 v = {stagew[ix], stagew[ix + 1], stagew[ix + 2], stagew[ix + 3]};
                braw[t][s] = v;
            }
#pragma unroll
        for (int s = 0; s < 8; ++s)
#pragma unroll
            for (int t = 0; t < 2; ++t)
                asm volatile("" : "+v"(braw[t][s]));

        fx4 cacc[3][2];
#pragma unroll
        for (int mt = 0; mt < 3; ++mt)
#pragma unroll
            for (int t = 0; t < 2; ++t) cacc[mt][t] = zero4;

#pragma unroll
        for (int s = 0; s < 8; ++s)
#pragma unroll
            for (int t = 0; t < 2; ++t) {
                bfx8 bf = __builtin_bit_cast(bfx8, braw[t][s]);
#pragma unroll
                for (int mt = 0; mt < 3; ++mt)
                    cacc[mt][t] = __builtin_amdgcn_mfma_f32_16x16x32_bf16(
                        __builtin_bit_cast(bfx8, afr[mt][s]), bf, cacc[mt][t], 0, 0, 0);
            }

        // magnitudes -> wave-private LDS
#pragma unroll
        for (int t = 0; t < 2; ++t)
#pragma unroll
            for (int mt = 0; mt < 3; ++mt) {
                float m0 = sqrtf(cacc[mt][t][0] * cacc[mt][t][0] +
                                 cacc[mt][t][1] * cacc[mt][t][1]);
                float m1 = sqrtf(cacc[mt][t][2] * cacc[mt][t][2] +
                                 cacc[mt][t][3] * cacc[mt][t][3]);
                unsigned u0 = __float_as_uint(m0), u1 = __float_as_uint(m1);
                unsigned pk = ((u0 + 0x8000u) >> 16) | ((u1 + 0x8000u) & 0xFFFF0000u);
                mag_lds[wave][t * 16 + n][4 * mt + q] = pk;
            }

        // mix
#pragma unroll
        for (int t = 0; t < 2; ++t) {
            ux4 raw = *(const ux4*)&mag_lds[wave][t * 16 + n][q * 4];
            bfx8 mb = __builtin_bit_cast(bfx8, raw);
#pragma unroll
            for (int mt = 0; mt < 2; ++mt)
                yacc[mt][t] = __builtin_amdgcn_mfma_f32_16x16x32_bf16(
                    wf[mt], mb, yacc[mt][t], 0, 0, 0);
        }

        // write next channel's staging into the other buffer, then barrier
        if (c < 31) {
            const int wb = ((c + 1) & 1) * STG_BUF_DW;
            *(ux4*)&stagew[wb + tid * 4] = nv0;
            *(ux4*)&stagew[wb + s1p * STG_REP_DW + off1 * 4] = nv1;
            if (tid < 64) *(ux4*)&stagew[wb + STG_REP_DW + (tid + 224) * 4] = nv2;
        }
        __syncthreads();
    }

    // ---- epilogue: y store + fused instance-norm partial stats ----------
    float* yp = ypart + (size_t)(b * 32) * 16384 + h * 128;
#pragma unroll
    for (int mt = 0; mt < 2; ++mt)
#pragma unroll
        for (int t = 0; t < 2; ++t) {
            const int w0 = px0 + t * 16 + n;
#pragma unroll
            for (int r = 0; r < 4; ++r)
                yp[(size_t)(mt * 16 + 4 * q + r) * 16384 + w0] = yacc[mt][t][r];
        }

    float sv[8], qv[8];
#pragma unroll
    for (int mt = 0; mt < 2; ++mt)
#pragma unroll
        for (int r = 0; r < 4; ++r) {
            float v0 = yacc[mt][0][r], v1 = yacc[mt][1][r];
            sv[mt * 4 + r] = v0 + v1;
            qv[mt * 4 + r] = v0 * v0 + v1 * v1;
        }
#pragma unroll
    for (int m = 1; m <= 8; m <<= 1)
#pragma unroll
        for (int i = 0; i < 8; ++i) {
            sv[i] += __shfl_xor(sv[i], m);
            qv[i] += __shfl_xor(qv[i], m);
        }
    if (n == 0) {
#pragma unroll
        for (int i = 0; i < 8; ++i) {
            stat_lds[wave][q][i]     = sv[i];
            stat_lds[wave][q][i + 8] = qv[i];
        }
    }
    __syncthreads();
    if (tid < 64) {
        int qq = tid >> 4, i = tid & 15;
        float acc = stat_lds[0][qq][i] + stat_lds[1][qq][i] +
                    stat_lds[2][qq][i] + stat_lds[3][qq][i];
        int kind = i >> 3, mt = (i >> 2) & 1, r = i & 3;
        int o = mt * 16 + 4 * qq + r;
        atomicAdd(&stats[(b * 32 + o) * 2 + kind], acc);
    }
}

// ---- normalize + transposed store via LDS tiles --------------------------
__global__ void inorm2(const float* __restrict__ ypart, const float* __restrict__ stats,
                       float* __restrict__ out)
{
    const int bid = blockIdx.x;                 // 2048 = 128 (b,o) x 16 tiles
    const int bo = bid >> 4, tile = bid & 15;
    const int h0 = (tile >> 2) * 32, w0 = (tile & 3) * 32;
    const float mean = stats[bo * 2] * (1.f / 16384.f);
    float var = stats[bo * 2 + 1] * (1.f / 16384.f) - mean * mean;
    const float rstd = rsqrtf(fmaxf(var, 0.f) + 1e-5f);

    const float* y0 = ypart + (size_t)bo * 16384;
    __shared__ float tilebuf[32][33];
    const int r = threadIdx.x >> 3, c4 = (threadIdx.x & 7) * 4;

    const size_t base = (size_t)(h0 + r) * 128 + w0 + c4;
    fx4 a = *(const fx4*)(y0 + base);
#pragma unroll
    for (int j = 0; j < 4; ++j)
        tilebuf[r][c4 + j] = (a[j] - mean) * rstd;
    __syncthreads();
    float* ob = out + (size_t)bo * 16384 + (size_t)(w0 + r) * 128 + h0 + c4;
    fx4 o4;
#pragma unroll
    for (int j = 0; j < 4; ++j) o4[j] = tilebuf[c4 + j][r];
    *(fx4*)ob = o4;
}

extern "C" void kernel_launch(void* const* d_in, const int* in_sizes, int n_in,
                              void* d_out, int out_size, void* d_ws, size_t ws_size,
                              hipStream_t stream)
{
    const float* x    = (const float*)d_in[0];
    const float* filt = (const float*)d_in[1];
    const float* w1   = (const float*)d_in[2];
    // d_in[3] = b1: cancels under instance norm, unused.
    float* out = (float*)d_out;
    char* ws = (char*)d_ws;

    unsigned*       xrep  = (unsigned*)ws;
    unsigned short* Aw    = (unsigned short*)(ws + A_OFF);
    unsigned short* w1b   = (unsigned short*)(ws + W1B_OFF);
    float*          yp    = (float*)(ws + YP_OFF);
    float*          stats = (float*)(ws + ST_OFF);

    prep<<<2048 + 178, 256, 0, stream>>>(x, filt, w1, xrep, Aw, w1b, stats);
    conv_mix<<<512, 256, 0, stream>>>((const unsigned short*)xrep, Aw, w1b, yp, stats);
    inorm2<<<2048, 256, 0, stream>>>(yp, stats, out);
}

// Round 7
// 127.186 us; speedup vs baseline: 1.1015x; 1.1015x over previous
//
#include <hip/hip_runtime.h>

// ---------------------------------------------------------------------------
// EnhancedBlockGabor on MI355X (gfx950)
//   prep     : x -> 2 column-phase-shifted padded bf16 replicas; filters ->
//              A bf16 [48][256]; w1 -> bf16 [32][32][32]; zero stats
//   conv_mix : per (b,h) block, 32 channels, BARRIER-FREE main loop:
//              each wave stages its own 48-px window (2 reps x 16 rows) into
//              wave-private LDS (double-buffered), gathers B-fragments,
//              mfma conv + |.| + mixing GEMM; epilogue: y + fused stats
//   inorm2   : normalize + H<->W transpose via 32x32 LDS tiles
// b1 ignored: per-channel constant cancels under instance norm.
// R7: R6 falsified the VALU theory (VALUBusy counts MFMA on gfx950; true
// pipes all <45% busy). Kernel is latency-bound at 2 waves/SIMD with a
// __syncthreads-drain per c-iter. Staging is now WAVE-PRIVATE -> zero
// main-loop barriers -> cross-iteration pipelining within each wave.
// Also: v_sqrt_f32 via asm (1 inst vs ~7), prep divisions removed.
// ---------------------------------------------------------------------------

typedef __attribute__((ext_vector_type(8))) short bfx8;
typedef __attribute__((ext_vector_type(4))) float fx4;
typedef __attribute__((ext_vector_type(4))) unsigned ux4;

#define NREP   2
#define RPITCH 144
#define RROWS  144
#define IMG_SH (RROWS * RPITCH)            // 20736 shorts per padded image
#define REP_SH (128 * IMG_SH)              // 2,654,208 shorts per replica
#define XREP_SH (NREP * REP_SH)

#define A_OFF    ((size_t)XREP_SH * 2)
#define W1B_OFF  (A_OFF + (size_t)48 * 256 * 2)
#define YP_OFF   (W1B_OFF + (size_t)32 * 32 * 32 * 2)
#define ST_OFF   (YP_OFF + (size_t)128 * 16384 * 4)
// total ws: ~19.3 MiB

// wave-private staging (dwords): row stride 40 (==8 mod 32), rep stride 656
// (==16 mod 32) -> same all-2-way conflict-free pattern as R5's shared layout.
#define WROW_DW  40
#define WREP_DW  656                       // 16*40 + 16 pad
#define WBUF_DW  (2 * WREP_DW)             // 1312 dw per buffer
#define WWAVE_DW (2 * WBUF_DW)             // 2624 dw per wave (two buffers)

__device__ __forceinline__ unsigned short f2bf(float f) {
    unsigned u = __float_as_uint(f);
    u = (u + 0x7FFFu + ((u >> 16) & 1u)) >> 16;   // RTNE
    return (unsigned short)u;
}

__device__ __forceinline__ float fsqrt(float x) {
    float r;
    asm("v_sqrt_f32 %0, %1" : "=v"(r) : "v"(x));
    return r;
}

// ---- merged prep: 2 replicas + A + w1b + stats-zero ----------------------
__global__ void prep(const float* __restrict__ x, const float* __restrict__ filt,
                     const float* __restrict__ w1, unsigned* __restrict__ xrep,
                     unsigned short* __restrict__ A, unsigned short* __restrict__ w1b,
                     float* __restrict__ stats)
{
    const int bid = blockIdx.x;
    if (bid < 2048) {
        // bid -> (phi, img, row-group of 18); no runtime divisions
        const int phi = bid & 1, img = (bid >> 1) & 127, rg = bid >> 8;
        const unsigned obase = (unsigned)phi * (REP_SH / 2) + img * (IMG_SH / 2)
                             + rg * 18 * 72;
        for (int j = threadIdx.x; j < 18 * 72; j += 256) {
            int jr = j / 72;                       // const-divisor -> magic mul
            int pd = j - jr * 72;
            int r  = rg * 18 + jr;
            int c0 = 2 * pd + phi;
            float v0 = 0.f, v1 = 0.f;
            int rr = r - 7;
            if (rr >= 0 && rr < 128) {
                const float* row = x + ((size_t)img * 128 + rr) * 128;
                int cc0 = c0 - 7;
                if (cc0 >= 0 && cc0 < 128) v0 = row[cc0];
                int cc1 = c0 - 6;
                if (cc1 >= 0 && cc1 < 128) v1 = row[cc1];
            }
            xrep[obase + j] = (unsigned)f2bf(v0) | ((unsigned)f2bf(v1) << 16);
        }
    } else {
        int t = (bid - 2048) * 256 + threadIdx.x;
        if (t < 48 * 256) {
            int f = t >> 8, k = t & 255;
            int ky = k >> 4, kx = k & 15;
            float v = 0.f;
            if (ky < 15 && kx < 15) v = filt[(f * 15 + ky) * 15 + kx];
            A[t] = f2bf(v);
        } else if (t < 48 * 256 + 32 * 32 * 32) {
            int j = t - 48 * 256;
            int c = j >> 10, o = (j >> 5) & 31, so = j & 31;
            float v = (so < 24) ? w1[o * 768 + c * 24 + so] : 0.f;
            w1b[j] = f2bf(v);
        } else if (t < 48 * 256 + 32 * 32 * 32 + 256) {
            stats[t - (48 * 256 + 32 * 32 * 32)] = 0.f;
        }
    }
}

// ---- fused conv + magnitude + channel-mix + stats ------------------------
// grid 512 = 4 b x 128 h, XCD-swizzled. 2 blocks/CU, one pass.
// NO __syncthreads in the channel loop: all LDS is wave-private.
__global__ void __attribute__((amdgpu_waves_per_eu(2, 2)))
__launch_bounds__(256)
conv_mix(const unsigned short* __restrict__ xrep,
         const unsigned short* __restrict__ Aw,
         const unsigned short* __restrict__ w1b,
         float* __restrict__ ypart, float* __restrict__ stats)
{
    __shared__ unsigned stagew[4 * WWAVE_DW];      // 41,984 B, wave-private
    __shared__ unsigned mag_lds[4][32][20];        // 10,240 B, wave-private
    __shared__ float stat_lds[4][4][16];           // 1 KB

    const int tid  = threadIdx.x;
    const int lane = tid & 63;
    const int wave = tid >> 6;
    const int n    = lane & 15;                    // MFMA row(A) / col(B,D)
    const int q    = lane >> 4;                    // MFMA k-octet / D row group

    const int bid = blockIdx.x;                    // xcd = bid & 7
    const int b   = (bid >> 1) & 3;
    const int h   = (bid & 1) * 64 + (bid >> 3);

    if (lane < 32) {                               // zero so=24..31 pads
        ux4 z4 = {0u, 0u, 0u, 0u};
        *(ux4*)&mag_lds[wave][lane][12] = z4;
    }

    // A fragments pinned (land in AGPRs; MFMA reads A from AGPR on gfx950)
    ux4 afr[3][8];
#pragma unroll
    for (int mt = 0; mt < 3; ++mt)
#pragma unroll
        for (int s = 0; s < 8; ++s)
            afr[mt][s] = *(const ux4*)(Aw + ((mt * 16 + n) * 256 + s * 32 + q * 8));
#pragma unroll
    for (int mt = 0; mt < 3; ++mt)
#pragma unroll
        for (int s = 0; s < 8; ++s)
            asm volatile("" : "+v"(afr[mt][s]));

    const int px0 = wave * 32;
    const int p   = n & 1;                         // phase replica
    // fragment base (dwords); per use: + buf*WBUF_DW + s*2*WROW_DW + t*8
    const int fbase = wave * WWAVE_DW + p * WREP_DW + (q >> 1) * WROW_DW
                    + ((n - p) >> 1) + (q & 1) * 4;

    // wave-private staging map: 3 slots of 16B per lane covering
    // 2 reps x 16 rows x 6 slots (96 B/row = px0..px0+47)
    int g_off[3], l_off[3];
#pragma unroll
    for (int i = 0; i < 3; ++i) {
        int slot = i * 64 + lane;
        int rep  = slot >= 96;
        int rem  = slot - 96 * rep;
        int row  = rem / 6;                        // const divisor
        int sl   = rem - row * 6;
        g_off[i] = rep * REP_SH + (h + row) * RPITCH + px0 + sl * 8;
        l_off[i] = wave * WWAVE_DW + rep * WREP_DW + row * WROW_DW + sl * 4;
    }
    const int imgbase0 = (b * 32) * IMG_SH;        // shorts, channel 0

    const fx4 zero4 = {0.f, 0.f, 0.f, 0.f};
    fx4 yacc[2][2];
#pragma unroll
    for (int mt = 0; mt < 2; ++mt)
#pragma unroll
        for (int t = 0; t < 2; ++t) yacc[mt][t] = zero4;

    // prologue: stage channel 0 into buf 0 (wave-private; no barrier)
    {
        const unsigned short* g = xrep + imgbase0;
#pragma unroll
        for (int i = 0; i < 3; ++i)
            *(ux4*)&stagew[l_off[i]] = *(const ux4*)(g + g_off[i]);
    }

    for (int c = 0; c < 32; ++c) {
        // issue next channel's staging loads (land during compute)
        ux4 nv[3];
        if (c < 31) {
            const unsigned short* g = xrep + imgbase0 + (c + 1) * IMG_SH;
#pragma unroll
            for (int i = 0; i < 3; ++i)
                nv[i] = *(const ux4*)(g + g_off[i]);
        }

        bfx8 wf[2];
#pragma unroll
        for (int mt = 0; mt < 2; ++mt)
            wf[mt] = *(const bfx8*)(w1b + ((c * 32 + mt * 16 + n) * 32 + q * 8));

        // batch-load ALL 16 B-fragments from wave-private LDS, pin
        const int fb = fbase + (c & 1) * WBUF_DW;
        ux4 braw[2][8];
#pragma unroll
        for (int s = 0; s < 8; ++s)
#pragma unroll
            for (int t = 0; t < 2; ++t) {
                const int ix = fb + s * (2 * WROW_DW) + t * 8;
                ux4 v = {stagew[ix], stagew[ix + 1], stagew[ix + 2], stagew[ix + 3]};
                braw[t][s] = v;
            }
#pragma unroll
        for (int s = 0; s < 8; ++s)
#pragma unroll
            for (int t = 0; t < 2; ++t)
                asm volatile("" : "+v"(braw[t][s]));

        fx4 cacc[3][2];
#pragma unroll
        for (int mt = 0; mt < 3; ++mt)
#pragma unroll
            for (int t = 0; t < 2; ++t) cacc[mt][t] = zero4;

#pragma unroll
        for (int s = 0; s < 8; ++s)
#pragma unroll
            for (int t = 0; t < 2; ++t) {
                bfx8 bf = __builtin_bit_cast(bfx8, braw[t][s]);
#pragma unroll
                for (int mt = 0; mt < 3; ++mt)
                    cacc[mt][t] = __builtin_amdgcn_mfma_f32_16x16x32_bf16(
                        __builtin_bit_cast(bfx8, afr[mt][s]), bf, cacc[mt][t], 0, 0, 0);
            }

        // magnitudes -> wave-private LDS (in-order DS within wave, no sync)
#pragma unroll
        for (int t = 0; t < 2; ++t)
#pragma unroll
            for (int mt = 0; mt < 3; ++mt) {
                float m0 = fsqrt(cacc[mt][t][0] * cacc[mt][t][0] +
                                 cacc[mt][t][1] * cacc[mt][t][1]);
                float m1 = fsqrt(cacc[mt][t][2] * cacc[mt][t][2] +
                                 cacc[mt][t][3] * cacc[mt][t][3]);
                unsigned u0 = __float_as_uint(m0), u1 = __float_as_uint(m1);
                unsigned pk = ((u0 + 0x8000u) >> 16) | ((u1 + 0x8000u) & 0xFFFF0000u);
                mag_lds[wave][t * 16 + n][4 * mt + q] = pk;
            }

        // mix
#pragma unroll
        for (int t = 0; t < 2; ++t) {
            ux4 raw = *(const ux4*)&mag_lds[wave][t * 16 + n][q * 4];
            bfx8 mb = __builtin_bit_cast(bfx8, raw);
#pragma unroll
            for (int mt = 0; mt < 2; ++mt)
                yacc[mt][t] = __builtin_amdgcn_mfma_f32_16x16x32_bf16(
                    wf[mt], mb, yacc[mt][t], 0, 0, 0);
        }

        // write next channel into the other wave-private buffer (no sync)
        if (c < 31) {
            const int wb = ((c + 1) & 1) * WBUF_DW;
#pragma unroll
            for (int i = 0; i < 3; ++i)
                *(ux4*)&stagew[wb + l_off[i]] = nv[i];
        }
    }

    // ---- epilogue: y store + fused instance-norm partial stats ----------
    float* yp = ypart + (size_t)(b * 32) * 16384 + h * 128;
#pragma unroll
    for (int mt = 0; mt < 2; ++mt)
#pragma unroll
        for (int t = 0; t < 2; ++t) {
            const int w0 = px0 + t * 16 + n;
#pragma unroll
            for (int r = 0; r < 4; ++r)
                yp[(size_t)(mt * 16 + 4 * q + r) * 16384 + w0] = yacc[mt][t][r];
        }

    float sv[8], qv[8];
#pragma unroll
    for (int mt = 0; mt < 2; ++mt)
#pragma unroll
        for (int r = 0; r < 4; ++r) {
            float v0 = yacc[mt][0][r], v1 = yacc[mt][1][r];
            sv[mt * 4 + r] = v0 + v1;
            qv[mt * 4 + r] = v0 * v0 + v1 * v1;
        }
#pragma unroll
    for (int m = 1; m <= 8; m <<= 1)
#pragma unroll
        for (int i = 0; i < 8; ++i) {
            sv[i] += __shfl_xor(sv[i], m);
            qv[i] += __shfl_xor(qv[i], m);
        }
    if (n == 0) {
#pragma unroll
        for (int i = 0; i < 8; ++i) {
            stat_lds[wave][q][i]     = sv[i];
            stat_lds[wave][q][i + 8] = qv[i];
        }
    }
    __syncthreads();
    if (tid < 64) {
        int qq = tid >> 4, i = tid & 15;
        float acc = stat_lds[0][qq][i] + stat_lds[1][qq][i] +
                    stat_lds[2][qq][i] + stat_lds[3][qq][i];
        int kind = i >> 3, mt = (i >> 2) & 1, r = i & 3;
        int o = mt * 16 + 4 * qq + r;
        atomicAdd(&stats[(b * 32 + o) * 2 + kind], acc);
    }
}

// ---- normalize + transposed store via LDS tiles --------------------------
__global__ void inorm2(const float* __restrict__ ypart, const float* __restrict__ stats,
                       float* __restrict__ out)
{
    const int bid = blockIdx.x;                 // 2048 = 128 (b,o) x 16 tiles
    const int bo = bid >> 4, tile = bid & 15;
    const int h0 = (tile >> 2) * 32, w0 = (tile & 3) * 32;
    const float mean = stats[bo * 2] * (1.f / 16384.f);
    float var = stats[bo * 2 + 1] * (1.f / 16384.f) - mean * mean;
    const float rstd = rsqrtf(fmaxf(var, 0.f) + 1e-5f);

    const float* y0 = ypart + (size_t)bo * 16384;
    __shared__ float tilebuf[32][33];
    const int r = threadIdx.x >> 3, c4 = (threadIdx.x & 7) * 4;

    const size_t base = (size_t)(h0 + r) * 128 + w0 + c4;
    fx4 a = *(const fx4*)(y0 + base);
#pragma unroll
    for (int j = 0; j < 4; ++j)
        tilebuf[r][c4 + j] = (a[j] - mean) * rstd;
    __syncthreads();
    float* ob = out + (size_t)bo * 16384 + (size_t)(w0 + r) * 128 + h0 + c4;
    fx4 o4;
#pragma unroll
    for (int j = 0; j < 4; ++j) o4[j] = tilebuf[c4 + j][r];
    *(fx4*)ob = o4;
}

extern "C" void kernel_launch(void* const* d_in, const int* in_sizes, int n_in,
                              void* d_out, int out_size, void* d_ws, size_t ws_size,
                              hipStream_t stream)
{
    const float* x    = (const float*)d_in[0];
    const float* filt = (const float*)d_in[1];
    const float* w1   = (const float*)d_in[2];
    // d_in[3] = b1: cancels under instance norm, unused.
    float* out = (float*)d_out;
    char* ws = (char*)d_ws;

    unsigned*       xrep  = (unsigned*)ws;
    unsigned short* Aw    = (unsigned short*)(ws + A_OFF);
    unsigned short* w1b   = (unsigned short*)(ws + W1B_OFF);
    float*          yp    = (float*)(ws + YP_OFF);
    float*          stats = (float*)(ws + ST_OFF);

    prep<<<2048 + 178, 256, 0, stream>>>(x, filt, w1, xrep, Aw, w1b, stats);
    conv_mix<<<512, 256, 0, stream>>>((const unsigned short*)xrep, Aw, w1b, yp, stats);
    inorm2<<<2048, 256, 0, stream>>>(yp, stats, out);
}

// Round 8
// 126.221 us; speedup vs baseline: 1.1099x; 1.0076x over previous
//
#include <hip/hip_runtime.h>

// ---------------------------------------------------------------------------
// EnhancedBlockGabor on MI355X (gfx950)
//   prep     : x -> 2 column-phase-shifted padded bf16 replicas; filters ->
//              A bf16 [48][256]; w1 -> bf16 [32][32][32]; zero stats
//   conv_mix : per (b,h) block, 32 channels, barrier-free main loop, all LDS
//              wave-private. R8: software-pipelined within each wave --
//              (1) rotated s-loop: B-fragments for s+1 load from LDS while
//              MFMAs of s issue (unpinned, fine-grained lgkmcnt), (2) mix
//              GEMM deferred one channel via double-buffered mag LDS so the
//              mag write->read latency leaves the dependent chain.
//   inorm2   : normalize + H<->W transpose via 32x32 LDS tiles
// b1 ignored: per-channel constant cancels under instance norm.
// ---------------------------------------------------------------------------

typedef __attribute__((ext_vector_type(8))) short bfx8;
typedef __attribute__((ext_vector_type(4))) float fx4;
typedef __attribute__((ext_vector_type(4))) unsigned ux4;

#define NREP   2
#define RPITCH 144
#define RROWS  144
#define IMG_SH (RROWS * RPITCH)            // 20736 shorts per padded image
#define REP_SH (128 * IMG_SH)              // 2,654,208 shorts per replica
#define XREP_SH (NREP * REP_SH)

#define A_OFF    ((size_t)XREP_SH * 2)
#define W1B_OFF  (A_OFF + (size_t)48 * 256 * 2)
#define YP_OFF   (W1B_OFF + (size_t)32 * 32 * 32 * 2)
#define ST_OFF   (YP_OFF + (size_t)128 * 16384 * 4)
// total ws: ~19.3 MiB

// wave-private staging (dwords): row stride 40 (==8 mod 32), rep stride 656
// (==16 mod 32) -> all fragment reads exactly 2-way banked (free, m136).
#define WROW_DW  40
#define WREP_DW  656
#define WBUF_DW  (2 * WREP_DW)             // 1312 dw per buffer
#define WWAVE_DW (2 * WBUF_DW)             // 2624 dw per wave (two buffers)

__device__ __forceinline__ unsigned short f2bf(float f) {
    unsigned u = __float_as_uint(f);
    u = (u + 0x7FFFu + ((u >> 16) & 1u)) >> 16;   // RTNE
    return (unsigned short)u;
}

__device__ __forceinline__ float fsqrt(float x) {
    float r;
    asm("v_sqrt_f32 %0, %1" : "=v"(r) : "v"(x));
    return r;
}

// ---- merged prep: 2 replicas + A + w1b + stats-zero ----------------------
__global__ void prep(const float* __restrict__ x, const float* __restrict__ filt,
                     const float* __restrict__ w1, unsigned* __restrict__ xrep,
                     unsigned short* __restrict__ A, unsigned short* __restrict__ w1b,
                     float* __restrict__ stats)
{
    const int bid = blockIdx.x;
    if (bid < 2048) {
        const int phi = bid & 1, img = (bid >> 1) & 127, rg = bid >> 8;
        const unsigned obase = (unsigned)phi * (REP_SH / 2) + img * (IMG_SH / 2)
                             + rg * 18 * 72;
        for (int j = threadIdx.x; j < 18 * 72; j += 256) {
            int jr = j / 72;
            int pd = j - jr * 72;
            int r  = rg * 18 + jr;
            int c0 = 2 * pd + phi;
            float v0 = 0.f, v1 = 0.f;
            int rr = r - 7;
            if (rr >= 0 && rr < 128) {
                const float* row = x + ((size_t)img * 128 + rr) * 128;
                int cc0 = c0 - 7;
                if (cc0 >= 0 && cc0 < 128) v0 = row[cc0];
                int cc1 = c0 - 6;
                if (cc1 >= 0 && cc1 < 128) v1 = row[cc1];
            }
            xrep[obase + j] = (unsigned)f2bf(v0) | ((unsigned)f2bf(v1) << 16);
        }
    } else {
        int t = (bid - 2048) * 256 + threadIdx.x;
        if (t < 48 * 256) {
            int f = t >> 8, k = t & 255;
            int ky = k >> 4, kx = k & 15;
            float v = 0.f;
            if (ky < 15 && kx < 15) v = filt[(f * 15 + ky) * 15 + kx];
            A[t] = f2bf(v);
        } else if (t < 48 * 256 + 32 * 32 * 32) {
            int j = t - 48 * 256;
            int c = j >> 10, o = (j >> 5) & 31, so = j & 31;
            float v = (so < 24) ? w1[o * 768 + c * 24 + so] : 0.f;
            w1b[j] = f2bf(v);
        } else if (t < 48 * 256 + 32 * 32 * 32 + 256) {
            stats[t - (48 * 256 + 32 * 32 * 32)] = 0.f;
        }
    }
}

// ---- fused conv + magnitude + channel-mix + stats ------------------------
// grid 512 = 4 b x 128 h, XCD-swizzled. 2 blocks/CU, one pass, no main-loop
// barriers (all LDS wave-private).
__global__ void __attribute__((amdgpu_waves_per_eu(2, 2)))
__launch_bounds__(256)
conv_mix(const unsigned short* __restrict__ xrep,
         const unsigned short* __restrict__ Aw,
         const unsigned short* __restrict__ w1b,
         float* __restrict__ ypart, float* __restrict__ stats)
{
    __shared__ unsigned stagew[4 * WWAVE_DW];      // 41,984 B, wave-private
    __shared__ unsigned mag_lds[2][4][32][20];     // 20,480 B, double-buffered
    __shared__ float stat_lds[4][4][16];           // 1 KB

    const int tid  = threadIdx.x;
    const int lane = tid & 63;
    const int wave = tid >> 6;
    const int n    = lane & 15;                    // MFMA row(A) / col(B,D)
    const int q    = lane >> 4;                    // MFMA k-octet / D row group

    const int bid = blockIdx.x;                    // xcd = bid & 7
    const int b   = (bid >> 1) & 3;
    const int h   = (bid & 1) * 64 + (bid >> 3);

    if (lane < 32) {                               // zero so=24..31 pads (both bufs)
        ux4 z4 = {0u, 0u, 0u, 0u};
        *(ux4*)&mag_lds[0][wave][lane][12] = z4;
        *(ux4*)&mag_lds[1][wave][lane][12] = z4;
    }

    // A fragments pinned (land in AGPRs; MFMA reads A from AGPR on gfx950)
    ux4 afr[3][8];
#pragma unroll
    for (int mt = 0; mt < 3; ++mt)
#pragma unroll
        for (int s = 0; s < 8; ++s)
            afr[mt][s] = *(const ux4*)(Aw + ((mt * 16 + n) * 256 + s * 32 + q * 8));
#pragma unroll
    for (int mt = 0; mt < 3; ++mt)
#pragma unroll
        for (int s = 0; s < 8; ++s)
            asm volatile("" : "+v"(afr[mt][s]));

    const int px0 = wave * 32;
    const int p   = n & 1;                         // phase replica
    const int fbase = wave * WWAVE_DW + p * WREP_DW + (q >> 1) * WROW_DW
                    + ((n - p) >> 1) + (q & 1) * 4;

    // wave-private staging map: 3 slots of 16B per lane covering
    // 2 reps x 16 rows x 6 slots (96 B/row = px0..px0+47)
    int g_off[3], l_off[3];
#pragma unroll
    for (int i = 0; i < 3; ++i) {
        int slot = i * 64 + lane;
        int rep  = slot >= 96;
        int rem  = slot - 96 * rep;
        int row  = rem / 6;
        int sl   = rem - row * 6;
        g_off[i] = rep * REP_SH + (h + row) * RPITCH + px0 + sl * 8;
        l_off[i] = wave * WWAVE_DW + rep * WREP_DW + row * WROW_DW + sl * 4;
    }
    const int imgbase0 = (b * 32) * IMG_SH;        // shorts, channel 0

    const fx4 zero4 = {0.f, 0.f, 0.f, 0.f};
    fx4 yacc[2][2];
#pragma unroll
    for (int mt = 0; mt < 2; ++mt)
#pragma unroll
        for (int t = 0; t < 2; ++t) yacc[mt][t] = zero4;

    // prologue: stage channel 0 into buf 0 (wave-private; no barrier)
    {
        const unsigned short* g = xrep + imgbase0;
#pragma unroll
        for (int i = 0; i < 3; ++i)
            *(ux4*)&stagew[l_off[i]] = *(const ux4*)(g + g_off[i]);
    }

    bfx8 wfp[2];                                   // w1 frags for channel c-1

    for (int c = 0; c < 32; ++c) {
        // 1) issue next channel's staging loads (land during compute)
        ux4 nv[3];
        if (c < 31) {
            const unsigned short* g = xrep + imgbase0 + (c + 1) * IMG_SH;
#pragma unroll
            for (int i = 0; i < 3; ++i)
                nv[i] = *(const ux4*)(g + g_off[i]);
        }

        // 2) read previous channel's magnitudes (written a full iter ago)
        ux4 magp[2];
        if (c > 0) {
            const int pbuf = (c & 1) ^ 1;
#pragma unroll
            for (int t = 0; t < 2; ++t)
                magp[t] = *(const ux4*)&mag_lds[pbuf][wave][t * 16 + n][q * 4];
        }

        // 3) w1 fragments for channel c (used next iteration)
        bfx8 wfc[2];
#pragma unroll
        for (int mt = 0; mt < 2; ++mt)
            wfc[mt] = *(const bfx8*)(w1b + ((c * 32 + mt * 16 + n) * 32 + q * 8));

        // 4) rotated s-pipeline: preload frags s+1 while MFMAs of s issue
        const int fb = fbase + (c & 1) * WBUF_DW;
        ux4 braw[2][2];                            // [s parity][t]
#pragma unroll
        for (int t = 0; t < 2; ++t) {
            const int ix = fb + t * 8;
            ux4 v = {stagew[ix], stagew[ix + 1], stagew[ix + 2], stagew[ix + 3]};
            braw[0][t] = v;
        }

        fx4 cacc[3][2];
#pragma unroll
        for (int mt = 0; mt < 3; ++mt)
#pragma unroll
            for (int t = 0; t < 2; ++t) cacc[mt][t] = zero4;

#pragma unroll
        for (int s = 0; s < 8; ++s) {
            if (s < 7) {
#pragma unroll
                for (int t = 0; t < 2; ++t) {
                    const int ix = fb + (s + 1) * (2 * WROW_DW) + t * 8;
                    ux4 v = {stagew[ix], stagew[ix + 1],
                             stagew[ix + 2], stagew[ix + 3]};
                    braw[(s + 1) & 1][t] = v;
                }
            }
#pragma unroll
            for (int t = 0; t < 2; ++t) {
                bfx8 bf = __builtin_bit_cast(bfx8, braw[s & 1][t]);
#pragma unroll
                for (int mt = 0; mt < 3; ++mt)
                    cacc[mt][t] = __builtin_amdgcn_mfma_f32_16x16x32_bf16(
                        __builtin_bit_cast(bfx8, afr[mt][s]), bf, cacc[mt][t], 0, 0, 0);
            }
            // deferred mix for channel c-1, overlapped with conv MFMAs
            if (s == 1 && c > 0) {
#pragma unroll
                for (int t = 0; t < 2; ++t) {
                    bfx8 mb = __builtin_bit_cast(bfx8, magp[t]);
#pragma unroll
                    for (int mt = 0; mt < 2; ++mt)
                        yacc[mt][t] = __builtin_amdgcn_mfma_f32_16x16x32_bf16(
                            wfp[mt], mb, yacc[mt][t], 0, 0, 0);
                }
            }
        }

        // 5) magnitudes -> mag buffer (c&1); consumed next iteration
#pragma unroll
        for (int t = 0; t < 2; ++t)
#pragma unroll
            for (int mt = 0; mt < 3; ++mt) {
                float m0 = fsqrt(cacc[mt][t][0] * cacc[mt][t][0] +
                                 cacc[mt][t][1] * cacc[mt][t][1]);
                float m1 = fsqrt(cacc[mt][t][2] * cacc[mt][t][2] +
                                 cacc[mt][t][3] * cacc[mt][t][3]);
                unsigned u0 = __float_as_uint(m0), u1 = __float_as_uint(m1);
                unsigned pk = ((u0 + 0x8000u) >> 16) | ((u1 + 0x8000u) & 0xFFFF0000u);
                mag_lds[c & 1][wave][t * 16 + n][4 * mt + q] = pk;
            }

        // 6) write next channel's staging into the other buffer (no sync)
        if (c < 31) {
            const int wb = ((c + 1) & 1) * WBUF_DW;
#pragma unroll
            for (int i = 0; i < 3; ++i)
                *(ux4*)&stagew[wb + l_off[i]] = nv[i];
        }
#pragma unroll
        for (int mt = 0; mt < 2; ++mt) wfp[mt] = wfc[mt];
    }

    // final deferred mix (channel 31, buffer 1)
#pragma unroll
    for (int t = 0; t < 2; ++t) {
        ux4 raw = *(const ux4*)&mag_lds[1][wave][t * 16 + n][q * 4];
        bfx8 mb = __builtin_bit_cast(bfx8, raw);
#pragma unroll
        for (int mt = 0; mt < 2; ++mt)
            yacc[mt][t] = __builtin_amdgcn_mfma_f32_16x16x32_bf16(
                wfp[mt], mb, yacc[mt][t], 0, 0, 0);
    }

    // ---- epilogue: y store + fused instance-norm partial stats ----------
    float* yp = ypart + (size_t)(b * 32) * 16384 + h * 128;
#pragma unroll
    for (int mt = 0; mt < 2; ++mt)
#pragma unroll
        for (int t = 0; t < 2; ++t) {
            const int w0 = px0 + t * 16 + n;
#pragma unroll
            for (int r = 0; r < 4; ++r)
                yp[(size_t)(mt * 16 + 4 * q + r) * 16384 + w0] = yacc[mt][t][r];
        }

    float sv[8], qv[8];
#pragma unroll
    for (int mt = 0; mt < 2; ++mt)
#pragma unroll
        for (int r = 0; r < 4; ++r) {
            float v0 = yacc[mt][0][r], v1 = yacc[mt][1][r];
            sv[mt * 4 + r] = v0 + v1;
            qv[mt * 4 + r] = v0 * v0 + v1 * v1;
        }
#pragma unroll
    for (int m = 1; m <= 8; m <<= 1)
#pragma unroll
        for (int i = 0; i < 8; ++i) {
            sv[i] += __shfl_xor(sv[i], m);
            qv[i] += __shfl_xor(qv[i], m);
        }
    if (n == 0) {
#pragma unroll
        for (int i = 0; i < 8; ++i) {
            stat_lds[wave][q][i]     = sv[i];
            stat_lds[wave][q][i + 8] = qv[i];
        }
    }
    __syncthreads();
    if (tid < 64) {
        int qq = tid >> 4, i = tid & 15;
        float acc = stat_lds[0][qq][i] + stat_lds[1][qq][i] +
                    stat_lds[2][qq][i] + stat_lds[3][qq][i];
        int kind = i >> 3, mt = (i >> 2) & 1, r = i & 3;
        int o = mt * 16 + 4 * qq + r;
        atomicAdd(&stats[(b * 32 + o) * 2 + kind], acc);
    }
}

// ---- normalize + transposed store via LDS tiles --------------------------
__global__ void inorm2(const float* __restrict__ ypart, const float* __restrict__ stats,
                       float* __restrict__ out)
{
    const int bid = blockIdx.x;                 // 2048 = 128 (b,o) x 16 tiles
    const int bo = bid >> 4, tile = bid & 15;
    const int h0 = (tile >> 2) * 32, w0 = (tile & 3) * 32;
    const float mean = stats[bo * 2] * (1.f / 16384.f);
    float var = stats[bo * 2 + 1] * (1.f / 16384.f) - mean * mean;
    const float rstd = rsqrtf(fmaxf(var, 0.f) + 1e-5f);

    const float* y0 = ypart + (size_t)bo * 16384;
    __shared__ float tilebuf[32][33];
    const int r = threadIdx.x >> 3, c4 = (threadIdx.x & 7) * 4;

    const size_t base = (size_t)(h0 + r) * 128 + w0 + c4;
    fx4 a = *(const fx4*)(y0 + base);
#pragma unroll
    for (int j = 0; j < 4; ++j)
        tilebuf[r][c4 + j] = (a[j] - mean) * rstd;
    __syncthreads();
    float* ob = out + (size_t)bo * 16384 + (size_t)(w0 + r) * 128 + h0 + c4;
    fx4 o4;
#pragma unroll
    for (int j = 0; j < 4; ++j) o4[j] = tilebuf[c4 + j][r];
    *(fx4*)ob = o4;
}

extern "C" void kernel_launch(void* const* d_in, const int* in_sizes, int n_in,
                              void* d_out, int out_size, void* d_ws, size_t ws_size,
                              hipStream_t stream)
{
    const float* x    = (const float*)d_in[0];
    const float* filt = (const float*)d_in[1];
    const float* w1   = (const float*)d_in[2];
    // d_in[3] = b1: cancels under instance norm, unused.
    float* out = (float*)d_out;
    char* ws = (char*)d_ws;

    unsigned*       xrep  = (unsigned*)ws;
    unsigned short* Aw    = (unsigned short*)(ws + A_OFF);
    unsigned short* w1b   = (unsigned short*)(ws + W1B_OFF);
    float*          yp    = (float*)(ws + YP_OFF);
    float*          stats = (float*)(ws + ST_OFF);

    prep<<<2048 + 178, 256, 0, stream>>>(x, filt, w1, xrep, Aw, w1b, stats);
    conv_mix<<<512, 256, 0, stream>>>((const unsigned short*)xrep, Aw, w1b, yp, stats);
    inorm2<<<2048, 256, 0, stream>>>(yp, stats, out);
}